// Round 1
// baseline (100.386 us; speedup 1.0000x reference)
//
#include <hip/hip_runtime.h>

// MockSparseModel: logits[b,t,v] = boost if (mask[b,t]==1 && v==input_ids[b,t]) else 0
// B=8, S=512, V=32768 -> 4096 rows x 32768 fp32 = 512 MiB output, write-BW bound.

#define VOCAB 32768
#define ROWS  (8 * 512)
#define TPB   256
// floats per row / (threads * 4 floats per float4) = 32768 / 1024 = 32 iters
#define ITERS (VOCAB / (TPB * 4))

__global__ __launch_bounds__(TPB) void mock_sparse_scatter(
    const int* __restrict__ input_ids,
    const int* __restrict__ attention_mask,
    const float* __restrict__ boost_p,
    float* __restrict__ out)
{
    const int row = blockIdx.x;          // 0..4095  (b*S + t), wave-uniform
    const int tid = threadIdx.x;         // 0..255

    // Uniform per-row scalars (compiler emits s_load for these)
    const int  id    = input_ids[row];
    const bool valid = (attention_mask[row] == 1) && (id >= 0) && (id < VOCAB);
    const float boost = valid ? boost_p[0] : 0.0f;

    float4* outr = reinterpret_cast<float4*>(out + (size_t)row * VOCAB);

    #pragma unroll
    for (int j = 0; j < ITERS; ++j) {
        const int f4i = j * TPB + tid;   // float4 index within the row (coalesced)
        const int e0  = f4i * 4;         // first element index of this float4
        float4 v;
        v.x = (valid && id == e0 + 0) ? boost : 0.0f;
        v.y = (valid && id == e0 + 1) ? boost : 0.0f;
        v.z = (valid && id == e0 + 2) ? boost : 0.0f;
        v.w = (valid && id == e0 + 3) ? boost : 0.0f;
        outr[f4i] = v;
    }
}

extern "C" void kernel_launch(void* const* d_in, const int* in_sizes, int n_in,
                              void* d_out, int out_size, void* d_ws, size_t ws_size,
                              hipStream_t stream) {
    const int*   input_ids      = (const int*)d_in[0];
    const int*   attention_mask = (const int*)d_in[1];
    const float* boost          = (const float*)d_in[2];
    float*       out            = (float*)d_out;

    mock_sparse_scatter<<<ROWS, TPB, 0, stream>>>(input_ids, attention_mask, boost, out);
}

// Round 2
// 99.309 us; speedup vs baseline: 1.0108x; 1.0108x over previous
//
#include <hip/hip_runtime.h>

// MockSparseModel: logits[b,t,v] = boost if (mask[b,t]==1 && v==input_ids[b,t]) else 0
// B=8, S=512, V=32768 -> 4096 rows x 32768 fp32 = 512 MiB output, write-BW bound.
//
// Strategy: hot loop = pure float4 zero-fill (identical to rocclr fillBuffer's
// inner loop), then the ONE thread that zero-wrote the target float4 rewrites
// the single boosted element. Same-thread program-ordered WAW -> deterministic,
// no cross-block race, no barrier.

#define VOCAB 32768
#define ROWS  (8 * 512)
#define TPB   256
// float4s per row / threads = (32768/4) / 256 = 32 iters
#define ITERS (VOCAB / (TPB * 4))

__global__ __launch_bounds__(TPB) void mock_sparse_scatter(
    const int* __restrict__ input_ids,
    const int* __restrict__ attention_mask,
    const float* __restrict__ boost_p,
    float* __restrict__ out)
{
    const int row = blockIdx.x;          // 0..4095  (b*S + t), wave-uniform
    const int tid = threadIdx.x;         // 0..255

    float* __restrict__ rowp = out + (size_t)row * VOCAB;
    float4* __restrict__ outr = reinterpret_cast<float4*>(rowp);

    // Pure streaming zero-fill: one 16B store per iter, no per-lane compares.
    const float4 z = make_float4(0.0f, 0.0f, 0.0f, 0.0f);
    #pragma unroll
    for (int j = 0; j < ITERS; ++j) {
        outr[j * TPB + tid] = z;         // coalesced: wave writes 1 KiB/instr
    }

    // Fixup: wave-uniform scalars (s_load), at most one lane per block acts.
    const int  id    = input_ids[row];
    const bool valid = (attention_mask[row] == 1) && (id >= 0) && (id < VOCAB);
    // Owner = the thread that wrote float4 index (id>>2), i.e. tid == (id>>2) & 255.
    if (valid && ((id >> 2) & (TPB - 1)) == tid) {
        rowp[id] = boost_p[0];           // same thread wrote this float4 above
    }
}

extern "C" void kernel_launch(void* const* d_in, const int* in_sizes, int n_in,
                              void* d_out, int out_size, void* d_ws, size_t ws_size,
                              hipStream_t stream) {
    const int*   input_ids      = (const int*)d_in[0];
    const int*   attention_mask = (const int*)d_in[1];
    const float* boost          = (const float*)d_in[2];
    float*       out            = (float*)d_out;

    mock_sparse_scatter<<<ROWS, TPB, 0, stream>>>(input_ids, attention_mask, boost, out);
}

// Round 3
// 98.199 us; speedup vs baseline: 1.0223x; 1.0113x over previous
//
#include <hip/hip_runtime.h>

// MockSparseModel: logits[b,t,v] = boost if (mask[b,t]==1 && v==input_ids[b,t]) else 0
// B=8, S=512, V=32768 -> 4096 rows x 32768 fp32 = 512 MiB output, write-BW bound.
//
// Hot loop = pure float4 zero-fill; the ONE thread that zero-wrote the target
// float4 rewrites the boosted element afterwards (same-thread WAW, race-free).
//
// Round 2 lesson: VALU in the fill loop was NOT the bottleneck. New theory:
// all 4096 blocks march in lockstep, so concurrent stores sit at a constant
// 128 KiB stride (row*131072 + j*4096 + tid*16) -> HBM channel aliasing.
// Fix: rotate iteration phase per row so concurrent blocks hit 32 distinct
// 4 KiB offsets. Per-thread address SET is unchanged -> fixup owner unchanged.

#define VOCAB 32768
#define ROWS  (8 * 512)
#define TPB   256
// float4s per row / threads = (32768/4) / 256 = 32 iters
#define ITERS (VOCAB / (TPB * 4))

__global__ __launch_bounds__(TPB) void mock_sparse_scatter(
    const int* __restrict__ input_ids,
    const int* __restrict__ attention_mask,
    const float* __restrict__ boost_p,
    float* __restrict__ out)
{
    const int row = blockIdx.x;          // 0..4095  (b*S + t), wave-uniform
    const int tid = threadIdx.x;         // 0..255

    float* __restrict__ rowp = out + (size_t)row * VOCAB;
    float4* __restrict__ outr = reinterpret_cast<float4*>(rowp);

    // Per-row phase rotation: breaks the 128 KiB inter-block stride lockstep.
    const int phase = row & (ITERS - 1);   // 0..31, wave-uniform (SALU)

    const float4 z = make_float4(0.0f, 0.0f, 0.0f, 0.0f);
    #pragma unroll
    for (int j = 0; j < ITERS; ++j) {
        int jj = j + phase;
        jj = (jj >= ITERS) ? (jj - ITERS) : jj;   // (j + phase) % 32
        outr[jj * TPB + tid] = z;                 // coalesced 1 KiB/wave-instr
    }

    // Fixup: wave-uniform scalars (s_load), at most one lane per block acts.
    const int  id    = input_ids[row];
    const bool valid = (attention_mask[row] == 1) && (id >= 0) && (id < VOCAB);
    // Owner = thread that wrote float4 index (id>>2): tid == (id>>2) % 256.
    if (valid && ((id >> 2) & (TPB - 1)) == tid) {
        rowp[id] = boost_p[0];           // same thread wrote this float4 above
    }
}

extern "C" void kernel_launch(void* const* d_in, const int* in_sizes, int n_in,
                              void* d_out, int out_size, void* d_ws, size_t ws_size,
                              hipStream_t stream) {
    const int*   input_ids      = (const int*)d_in[0];
    const int*   attention_mask = (const int*)d_in[1];
    const float* boost          = (const float*)d_in[2];
    float*       out            = (float*)d_out;

    mock_sparse_scatter<<<ROWS, TPB, 0, stream>>>(input_ids, attention_mask, boost, out);
}